// Round 4
// baseline (333.346 us; speedup 1.0000x reference)
//
#include <hip/hip_runtime.h>
#include <hip/hip_bf16.h>

// Complex 2x nearest-neighbor upsample, PLANAR output layout:
//   out = stack([y.real, y.imag]) -> (2, B, 2H, 2W, C) float32
//   plane 0: out[ ((b*OH + h)*OW + w)*C + c ]             = x_re[b, h/2, w/2, c]
//   plane 1: out[ P + ((b*OH + h)*OW + w)*C + c ]         = x_im[b, h/2, w/2, c]
//   where P = B*OH*OW*C.
//
// One thread per (output pixel, 4-channel group): two float4 input loads,
// two float4 nontemporal stores (one per plane). All streams coalesced.
// n_planes derived from out_size at runtime (1 => real-only fallback).

#define BB 16
#define HH 128
#define WW 128
#define CC 64
#define OH (2 * HH)   // 256
#define OW (2 * WW)   // 256

typedef float vfloat4 __attribute__((ext_vector_type(4)));

__global__ __launch_bounds__(256) void complex_upsample2x_planar(
    const float* __restrict__ x_re,
    const float* __restrict__ x_im,
    float* __restrict__ out,
    unsigned plane_vec4,   // float4s per plane = B*OH*OW*C/4
    int n_planes) {
    const unsigned q = blockIdx.x * blockDim.x + threadIdx.x;
    if (q >= plane_vec4) return;

    const unsigned g    = q & (CC / 4 - 1);  // channel group (4 channels)
    const unsigned opix = q >> 4;            // output pixel
    const unsigned wo   = opix & (OW - 1);
    const unsigned rem  = opix >> 8;         // log2(OW)=8
    const unsigned ho   = rem & (OH - 1);
    const unsigned b    = rem >> 8;          // log2(OH)=8

    const unsigned hi = ho >> 1;
    const unsigned wi = wo >> 1;

    // input float4 index: (((b*H + hi)*W + wi)*C)/4 + g
    const unsigned in_q = ((((b << 7) + hi) << 7) + wi) * (CC / 4) + g;

    const vfloat4 re = *(reinterpret_cast<const vfloat4*>(x_re) + in_q);
    vfloat4* outv = reinterpret_cast<vfloat4*>(out);
    __builtin_nontemporal_store(re, outv + q);

    if (n_planes == 2) {
        const vfloat4 im = *(reinterpret_cast<const vfloat4*>(x_im) + in_q);
        __builtin_nontemporal_store(im, outv + plane_vec4 + q);
    }
}

extern "C" void kernel_launch(void* const* d_in, const int* in_sizes, int n_in,
                              void* d_out, int out_size, void* d_ws, size_t ws_size,
                              hipStream_t stream) {
    const float* x_re = (const float*)d_in[0];
    const float* x_im = (const float*)d_in[1];
    float* out = (float*)d_out;

    const unsigned plane_elems = BB * OH * OW * CC;           // 67,108,864
    const int n_planes = (out_size >= (int64_t)2 * plane_elems) ? 2 : 1;
    const unsigned plane_vec4 = plane_elems / 4;              // 16,777,216

    const int block = 256;
    const unsigned grid = (plane_vec4 + block - 1) / block;   // 65,536 blocks
    complex_upsample2x_planar<<<grid, block, 0, stream>>>(x_re, x_im, out,
                                                          plane_vec4, n_planes);
}